// Round 4
// baseline (269.560 us; speedup 1.0000x reference)
//
#include <hip/hip_runtime.h>
#include <stdint.h>

#define HW    3136
#define CH    256
#define NBAT  16
#define RDIM  2304          // CH * 9
#define NPOS  50176         // NBAT * HW
#define EPSV  1e-5f

typedef __bf16 bf16x8 __attribute__((ext_vector_type(8)));
typedef float  f32x4  __attribute__((ext_vector_type(4)));

__device__ __forceinline__ float bf2f(unsigned short s) {
    union { unsigned int u; float f; } z; z.u = ((unsigned int)s) << 16; return z.f;
}
__device__ __forceinline__ unsigned short f2bf(float f) {
    union { float f; unsigned int u; } z; z.f = f;
    unsigned int u = z.u;
    u += 0x7FFFu + ((u >> 16) & 1u);     // round-to-nearest-even
    return (unsigned short)(u >> 16);
}

__device__ __forceinline__ void gload_lds16(const void* g, void* l) {
    __builtin_amdgcn_global_load_lds(
        (const __attribute__((address_space(1))) unsigned int*)g,
        (__attribute__((address_space(3))) unsigned int*)l,
        16, 0, 0);
}

// ---------------- 1. transpose x [B,C,HW] f32 -> x_t [B,HW,C] bf16 ----------------
__global__ __launch_bounds__(256) void k_transpose(const float* __restrict__ x,
                                                   unsigned short* __restrict__ xt) {
    __shared__ float tile[64][65];
    int hw0 = blockIdx.x * 64;
    int c0  = blockIdx.y * 64;
    int b   = blockIdx.z;
    int tx = threadIdx.x & 63;
    int ty = threadIdx.x >> 6;
    const float* xp = x + ((size_t)(b * CH + c0)) * HW + hw0;
#pragma unroll
    for (int i = 0; i < 16; i++) {
        int c_l = ty + i * 4;
        tile[c_l][tx] = xp[(size_t)c_l * HW + tx];
    }
    __syncthreads();
    unsigned short* op = xt + ((size_t)(b * HW + hw0)) * CH + c0;
#pragma unroll
    for (int i = 0; i < 16; i++) {
        int hw_l = ty + i * 4;
        op[(size_t)hw_l * CH + tx] = f2bf(tile[tx][hw_l]);
    }
}

// ---------------- 2. weight [O,C,3,3] f32 -> W2[o][k*256+c] bf16 ----------------
__global__ __launch_bounds__(256) void k_w2(const float* __restrict__ w,
                                            unsigned short* __restrict__ w2) {
    int idx = blockIdx.x * 256 + threadIdx.x;   // exactly 589824 threads
    int c = idx & 255;
    int k = (idx >> 8) % 9;
    int o = idx / RDIM;
    w2[idx] = f2bf(w[o * RDIM + c * 9 + k]);
}

// ---------------- 3. sampling / im2col: S[p_loc][k*256+c] bf16 ----------------
// one wave per position, 4 channels per lane
__global__ __launch_bounds__(256) void k_sample(const unsigned short* __restrict__ xt,
                                                const float* __restrict__ off,
                                                unsigned short* __restrict__ S,
                                                int p_start) {
    int wid  = threadIdx.x >> 6;
    int lane = threadIdx.x & 63;
    int p = p_start + blockIdx.x * 4 + wid;
    int p_loc = p - p_start;
    int b  = p / HW;
    int hw = p % HW;
    int h = hw / 56;
    int w = hw % 56;
    int c0 = lane * 4;
    const unsigned short* xb = xt + (size_t)b * HW * CH;
    unsigned short* sp = S + (size_t)p_loc * RDIM + c0;
#pragma unroll
    for (int k = 0; k < 9; k++) {
        float offY = off[(b * 18 + 2 * k) * HW + hw];
        float offX = off[(b * 18 + 2 * k + 1) * HW + hw];
        float py = (float)(h + k / 3 - 1) + offY;
        float px = (float)(w + k % 3 - 1) + offX;
        float y0 = floorf(py), x0 = floorf(px);
        float wy1 = py - y0, wx1 = px - x0;
        float a0 = 0.f, a1 = 0.f, a2 = 0.f, a3 = 0.f;
#pragma unroll
        for (int dy = 0; dy < 2; dy++) {
            float ycf = y0 + (float)dy;
            bool vy = (ycf >= 0.f) && (ycf <= 55.f);
            int yi = min(max((int)ycf, 0), 55);
            float wy = dy ? wy1 : (1.f - wy1);
#pragma unroll
            for (int dx = 0; dx < 2; dx++) {
                float xcf = x0 + (float)dx;
                bool v = vy && (xcf >= 0.f) && (xcf <= 55.f);
                int xi = min(max((int)xcf, 0), 55);
                float wgt = v ? (wy * (dx ? wx1 : (1.f - wx1))) : 0.f;
                ushort4 s4 = *(const ushort4*)(xb + (size_t)(yi * 56 + xi) * CH + c0);
                a0 += wgt * bf2f(s4.x);
                a1 += wgt * bf2f(s4.y);
                a2 += wgt * bf2f(s4.z);
                a3 += wgt * bf2f(s4.w);
            }
        }
        ushort4 o4;
        o4.x = f2bf(a0); o4.y = f2bf(a1); o4.z = f2bf(a2); o4.w = f2bf(a3);
        *(ushort4*)(sp + k * 256) = o4;
    }
}

// ---------------- 4. GEMM: y[b][o][p] = sum_r W2[o][r] * S[p][r] ----------------
// M-tile=256 (all of O), N-tile=64, BK=64, 512 threads = 8 waves (4M x 2N of 64x32)
#define BK 64
__global__ __launch_bounds__(512) void k_gemm(const unsigned short* __restrict__ S,
                                              const unsigned short* __restrict__ W2,
                                              float* __restrict__ y,
                                              int b_start) {
    __shared__ __align__(16) unsigned short lA[256 * BK];  // 32 KB
    __shared__ __align__(16) unsigned short lB[64 * BK];   //  8 KB
    int t    = threadIdx.x;
    int wid  = t >> 6;
    int lane = t & 63;
    int n0    = blockIdx.x * 64;
    int b_loc = blockIdx.y;
    int b     = b_start + b_loc;
    const unsigned short* Sb = S + (size_t)b_loc * HW * RDIM;

    int m_off = (wid >> 1) * 64;
    int n_off = (wid & 1) * 32;
    int fr = lane & 15;
    int fq = lane >> 4;

    f32x4 acc[4][2];
#pragma unroll
    for (int m = 0; m < 4; m++)
#pragma unroll
        for (int n = 0; n < 2; n++)
            acc[m][n] = (f32x4){0.f, 0.f, 0.f, 0.f};

    for (int r0 = 0; r0 < RDIM; r0 += BK) {
        // stage A-tile 256x64 (2048 16B chunks), XOR-swizzled source, linear LDS dest
#pragma unroll
        for (int i = 0; i < 4; i++) {
            int q = t + 512 * i;
            int row = q >> 3;
            int part = (q & 7) ^ (row & 7);          // inverse swizzle on SOURCE
            const unsigned short* g = W2 + (size_t)row * RDIM + r0 + part * 8;
            gload_lds16(g, &lA[(size_t)(wid * 64 + 512 * i) * 8]);
        }
        // stage B-tile 64x64 (512 chunks)
        {
            int row = t >> 3;
            int part = (t & 7) ^ (row & 7);
            const unsigned short* g = Sb + (size_t)(n0 + row) * RDIM + r0 + part * 8;
            gload_lds16(g, &lB[(size_t)(wid * 64) * 8]);
        }
        __syncthreads();
#pragma unroll
        for (int kk = 0; kk < 2; kk++) {
            bf16x8 afr[4], bfr[2];
#pragma unroll
            for (int m = 0; m < 4; m++) {
                int row = m_off + m * 16 + fr;
                int slot = (kk * 4 + fq) ^ (row & 7);  // swizzled READ
                afr[m] = *(const bf16x8*)&lA[row * BK + slot * 8];
            }
#pragma unroll
            for (int n = 0; n < 2; n++) {
                int row = n_off + n * 16 + fr;
                int slot = (kk * 4 + fq) ^ (row & 7);
                bfr[n] = *(const bf16x8*)&lB[row * BK + slot * 8];
            }
#pragma unroll
            for (int m = 0; m < 4; m++)
#pragma unroll
                for (int n = 0; n < 2; n++)
                    acc[m][n] = __builtin_amdgcn_mfma_f32_16x16x32_bf16(afr[m], bfr[n], acc[m][n], 0, 0, 0);
        }
        __syncthreads();
    }

    float* yb = y + (size_t)b * CH * HW;
#pragma unroll
    for (int m = 0; m < 4; m++) {
        int o = m_off + m * 16 + fq * 4;
#pragma unroll
        for (int n = 0; n < 2; n++) {
            int p = n0 + n_off + n * 16 + fr;
#pragma unroll
            for (int j = 0; j < 4; j++)
                yb[(size_t)(o + j) * HW + p] = acc[m][n][j];
        }
    }
}

// ---------------- 5a. per-channel BN stats -> scale/shift ----------------
__global__ __launch_bounds__(256) void k_stats(const float* __restrict__ y,
                                               const float* __restrict__ gamma,
                                               const float* __restrict__ beta,
                                               float* __restrict__ scaleArr,
                                               float* __restrict__ shiftArr) {
    int o = blockIdx.x;
    int t = threadIdx.x;
    float s = 0.f, s2 = 0.f;
    for (int b = 0; b < NBAT; b++) {
        const float4* yp = (const float4*)(y + ((size_t)(b * CH + o)) * HW);
        for (int i = t; i < HW / 4; i += 256) {
            float4 v = yp[i];
            s  += v.x + v.y + v.z + v.w;
            s2 += v.x * v.x + v.y * v.y + v.z * v.z + v.w * v.w;
        }
    }
    __shared__ float r1[256], r2[256];
    r1[t] = s; r2[t] = s2;
    __syncthreads();
    for (int st = 128; st > 0; st >>= 1) {
        if (t < st) { r1[t] += r1[t + st]; r2[t] += r2[t + st]; }
        __syncthreads();
    }
    if (t == 0) {
        float inv = 1.f / (float)NPOS;
        float mean = r1[0] * inv;
        float var  = r2[0] * inv - mean * mean;
        float sc = gamma[o] * rsqrtf(var + EPSV);
        scaleArr[o] = sc;
        shiftArr[o] = beta[o] - mean * sc;
    }
}

// ---------------- 5b. normalize + ReLU (in place on d_out) ----------------
__global__ __launch_bounds__(256) void k_norm(float* __restrict__ y,
                                              const float* __restrict__ scaleArr,
                                              const float* __restrict__ shiftArr) {
    const int total4 = NBAT * CH * (HW / 4);
    for (int i = blockIdx.x * 256 + threadIdx.x; i < total4; i += gridDim.x * 256) {
        int o = (i / (HW / 4)) & 255;
        float sc = scaleArr[o], sh = shiftArr[o];
        float4 v = ((const float4*)y)[i];
        float4 r;
        r.x = fmaxf(v.x * sc + sh, 0.f);
        r.y = fmaxf(v.y * sc + sh, 0.f);
        r.z = fmaxf(v.z * sc + sh, 0.f);
        r.w = fmaxf(v.w * sc + sh, 0.f);
        ((float4*)y)[i] = r;
    }
}

extern "C" void kernel_launch(void* const* d_in, const int* in_sizes, int n_in,
                              void* d_out, int out_size, void* d_ws, size_t ws_size,
                              hipStream_t stream) {
    const float* x     = (const float*)d_in[0];
    const float* off   = (const float*)d_in[1];
    const float* wgt   = (const float*)d_in[2];
    const float* gamma = (const float*)d_in[3];
    const float* beta  = (const float*)d_in[4];
    float* out = (float*)d_out;     // also used as the pre-BN conv output buffer
    char* ws = (char*)d_ws;

    // workspace layout (all offsets 256B-aligned)
    unsigned short* W2 = (unsigned short*)(ws + 0);              //  1,179,648 B
    unsigned short* xt = (unsigned short*)(ws + 1179648);        // 25,690,112 B
    float* scaleArr    = (float*)(ws + 26869760);                //      1,024 B
    float* shiftArr    = (float*)(ws + 26870784);                //      1,024 B
    unsigned short* Sbuf = (unsigned short*)(ws + 26871808);     // rest: im2col S

    const size_t S_PER_BATCH = (size_t)HW * RDIM * 2;            // 14,450,688 B
    size_t avail = (ws_size > 26871808) ? ws_size - 26871808 : 0;
    int bpc = (int)(avail / S_PER_BATCH);
    if (bpc > 16) bpc = 16;
    if (bpc < 1)  bpc = 1;   // best effort; needs ws_size >= ~41.3 MB

    k_transpose<<<dim3(49, 4, 16), 256, 0, stream>>>(x, xt);
    k_w2<<<2304, 256, 0, stream>>>(wgt, W2);
    for (int b0 = 0; b0 < 16; b0 += bpc) {
        int nb = (16 - b0 < bpc) ? (16 - b0) : bpc;
        k_sample<<<nb * 784, 256, 0, stream>>>(xt, off, Sbuf, b0 * HW);
        k_gemm<<<dim3(49, nb), 512, 0, stream>>>(Sbuf, W2, out, b0);
    }
    k_stats<<<256, 256, 0, stream>>>(out, gamma, beta, scaleArr, shiftArr);
    k_norm<<<2048, 256, 0, stream>>>(out, scaleArr, shiftArr);
}

// Round 5
// 190.465 us; speedup vs baseline: 1.4153x; 1.4153x over previous
//
#include <hip/hip_runtime.h>
#include <stdint.h>

#define HW    3136
#define CH    256
#define NBAT  16
#define RDIM  2304          // CH * 9
#define NPOS  50176         // NBAT * HW
#define EPSV  1e-5f
#define NBLK  784           // 49 * 16
#define NCOL  1568          // NBLK * 2 halves

typedef __bf16 bf16x8 __attribute__((ext_vector_type(8)));
typedef float  f32x4  __attribute__((ext_vector_type(4)));
typedef unsigned int u32x4 __attribute__((ext_vector_type(4)));

__device__ __forceinline__ unsigned short f2bf(float f) {
    union { float f; unsigned int u; } z; z.f = f;
    unsigned int u = z.u;
    u += 0x7FFFu + ((u >> 16) & 1u);     // round-to-nearest-even
    return (unsigned short)(u >> 16);
}

__device__ __forceinline__ unsigned int cvtpk(float lo, float hi) {
    unsigned int r;
    asm("v_cvt_pk_bf16_f32 %0, %1, %2" : "=v"(r) : "v"(lo), "v"(hi));
    return r;
}

__device__ __forceinline__ void gload_lds16(const void* g, void* l) {
    __builtin_amdgcn_global_load_lds(
        (const __attribute__((address_space(1))) unsigned int*)g,
        (__attribute__((address_space(3))) unsigned int*)l,
        16, 0, 0);
}

// ---------------- 1. transpose x [B,C,HW] f32 -> x_t [B,HW,C] bf16 ----------------
__global__ __launch_bounds__(256) void k_transpose(const float* __restrict__ x,
                                                   unsigned short* __restrict__ xt) {
    __shared__ float tile[64][65];
    int hw0 = blockIdx.x * 64;
    int c0  = blockIdx.y * 64;
    int b   = blockIdx.z;
    int tx = threadIdx.x & 63;
    int ty = threadIdx.x >> 6;
    const float* xp = x + ((size_t)(b * CH + c0)) * HW + hw0;
#pragma unroll
    for (int i = 0; i < 16; i++) {
        int c_l = ty + i * 4;
        tile[c_l][tx] = xp[(size_t)c_l * HW + tx];
    }
    __syncthreads();
    unsigned short* op = xt + ((size_t)(b * HW + hw0)) * CH + c0;
#pragma unroll
    for (int i = 0; i < 16; i++) {
        int hw_l = ty + i * 4;
        op[(size_t)hw_l * CH + tx] = f2bf(tile[tx][hw_l]);
    }
}

// ---------------- 2. weight [O,C,3,3] f32 -> W2[o][k*256+c] bf16 ----------------
__global__ __launch_bounds__(256) void k_w2(const float* __restrict__ w,
                                            unsigned short* __restrict__ w2) {
    int idx = blockIdx.x * 256 + threadIdx.x;   // exactly 589824 threads
    int c = idx & 255;
    int k = (idx >> 8) % 9;
    int o = idx / RDIM;
    w2[idx] = f2bf(w[o * RDIM + c * 9 + k]);
}

// ---------------- 3. fused im2col-sample + GEMM + BN partial sums ----------------
// grid (49, 16), 512 threads = 8 waves. M-tile=256 (all o), N-tile=64 positions.
// Per K-step (BK=64): stage A (W2) via global_load_lds; compute B by bilinear
// gather from x_t in registers, ds_write swizzled; 16 MFMA per wave.
#define BK 64
__global__ __launch_bounds__(512) void k_fgemm(const unsigned short* __restrict__ xt,
                                               const float* __restrict__ off,
                                               const unsigned short* __restrict__ W2,
                                               float* __restrict__ y,
                                               float* __restrict__ psum_s,
                                               float* __restrict__ psum_q) {
    __shared__ __align__(16) unsigned short lA[256 * BK];  // 32 KB
    __shared__ __align__(16) unsigned short lB[64 * BK];   //  8 KB
    __shared__ float2 smeta[4][64];                        //  2 KB
    int t    = threadIdx.x;
    int wid  = t >> 6;
    int lane = t & 63;
    int n0   = blockIdx.x * 64;
    int b    = blockIdx.y;
    const unsigned short* xb = xt + (size_t)b * HW * CH;

    int m_off = (wid >> 1) * 64;
    int n_off = (wid & 1) * 32;
    int fr = lane & 15;
    int fq = lane >> 4;

    int bp  = t >> 3;    // B-fill: position 0..63
    int bcg = t & 7;     // B-fill: channel group (8 ch)
    unsigned short* lbdst = &lB[bp * BK + ((bcg ^ (bp & 7)) * 8)];

    f32x4 acc[4][2];
#pragma unroll
    for (int m = 0; m < 4; m++)
#pragma unroll
        for (int n = 0; n < 2; n++)
            acc[m][n] = (f32x4){0.f, 0.f, 0.f, 0.f};

    for (int tap = 0; tap < 9; tap++) {
        // --- per-tap bilinear meta (wave 0) ---
        if (t < 64) {
            int hw = n0 + t;
            int h = hw / 56, w = hw - h * 56;
            float offY = off[((size_t)(b * 18 + 2 * tap)) * HW + hw];
            float offX = off[((size_t)(b * 18 + 2 * tap + 1)) * HW + hw];
            float py = (float)(h + tap / 3 - 1) + offY;
            float px = (float)(w + tap % 3 - 1) + offX;
            float y0f = floorf(py), x0f = floorf(px);
            float fy = py - y0f, fx = px - x0f;
            float wy[2] = {1.f - fy, fy};
            float wx[2] = {1.f - fx, fx};
#pragma unroll
            for (int j = 0; j < 4; j++) {
                int dy = j >> 1, dx = j & 1;
                float ycf = y0f + (float)dy, xcf = x0f + (float)dx;
                bool v = (ycf >= 0.f) && (ycf <= 55.f) && (xcf >= 0.f) && (xcf <= 55.f);
                int yi = min(max((int)ycf, 0), 55);
                int xi = min(max((int)xcf, 0), 55);
                float wgt = v ? wy[dy] * wx[dx] : 0.f;
                smeta[j][t] = make_float2(__int_as_float(yi * 56 + xi), wgt);
            }
        }
        __syncthreads();
        // hoist meta for my B-fill position into registers (reused 4 K-steps)
        int   cidx[4];
        float cwgt[4];
#pragma unroll
        for (int j = 0; j < 4; j++) {
            float2 m2 = smeta[j][bp];
            cidx[j] = __float_as_int(m2.x);
            cwgt[j] = m2.y;
        }

#pragma unroll
        for (int kk4 = 0; kk4 < 4; kk4++) {
            int r0 = tap * 256 + kk4 * 64;
            // stage A-tile 256x64 (async, source-swizzled, linear LDS dest)
#pragma unroll
            for (int i = 0; i < 4; i++) {
                int q = t + 512 * i;
                int row = q >> 3;
                int part = (q & 7) ^ (row & 7);
                gload_lds16(W2 + (size_t)row * RDIM + r0 + part * 8,
                            &lA[(size_t)(wid * 64 + 512 * i) * 8]);
            }
            // B-fill: bilinear blend of 8 channels for my position
            {
                int c0 = kk4 * 64 + bcg * 8;
                float al[4] = {0.f, 0.f, 0.f, 0.f};
                float ah[4] = {0.f, 0.f, 0.f, 0.f};
#pragma unroll
                for (int j = 0; j < 4; j++) {
                    u32x4 cv = *(const u32x4*)(xb + (size_t)cidx[j] * CH + c0);
                    float wj = cwgt[j];
#pragma unroll
                    for (int i = 0; i < 4; i++) {
                        float lo = __uint_as_float(cv[i] << 16);
                        float hi = __uint_as_float(cv[i] & 0xffff0000u);
                        al[i] = fmaf(wj, lo, al[i]);
                        ah[i] = fmaf(wj, hi, ah[i]);
                    }
                }
                u32x4 ov;
#pragma unroll
                for (int i = 0; i < 4; i++) ov[i] = cvtpk(al[i], ah[i]);
                *(u32x4*)lbdst = ov;
            }
            __syncthreads();
            // MFMA
#pragma unroll
            for (int kk = 0; kk < 2; kk++) {
                bf16x8 afr[4], bfr[2];
#pragma unroll
                for (int m = 0; m < 4; m++) {
                    int row = m_off + m * 16 + fr;
                    int slot = (kk * 4 + fq) ^ (row & 7);
                    afr[m] = *(const bf16x8*)&lA[row * BK + slot * 8];
                }
#pragma unroll
                for (int n = 0; n < 2; n++) {
                    int row = n_off + n * 16 + fr;
                    int slot = (kk * 4 + fq) ^ (row & 7);
                    bfr[n] = *(const bf16x8*)&lB[row * BK + slot * 8];
                }
#pragma unroll
                for (int m = 0; m < 4; m++)
#pragma unroll
                    for (int n = 0; n < 2; n++)
                        acc[m][n] = __builtin_amdgcn_mfma_f32_16x16x32_bf16(afr[m], bfr[n], acc[m][n], 0, 0, 0);
            }
            __syncthreads();
        }
    }

    // --- y write (pre-BN conv output) ---
    float* yb = y + (size_t)b * CH * HW;
#pragma unroll
    for (int m = 0; m < 4; m++) {
        int o = m_off + m * 16 + fq * 4;
#pragma unroll
        for (int n = 0; n < 2; n++) {
            int p = n0 + n_off + n * 16 + fr;
#pragma unroll
            for (int j = 0; j < 4; j++)
                yb[(size_t)(o + j) * HW + p] = acc[m][n][j];
        }
    }

    // --- BN partial sums: reduce over n and fr within each fq group ---
    int blk2 = (b * 49 + blockIdx.x) * 2 + (wid & 1);
#pragma unroll
    for (int m = 0; m < 4; m++)
#pragma unroll
        for (int j = 0; j < 4; j++) {
            float s = acc[m][0][j] + acc[m][1][j];
            float q = acc[m][0][j] * acc[m][0][j] + acc[m][1][j] * acc[m][1][j];
#pragma unroll
            for (int msk = 1; msk < 16; msk <<= 1) {
                s += __shfl_xor(s, msk);
                q += __shfl_xor(q, msk);
            }
            if (fr == 0) {
                int o = m_off + m * 16 + fq * 4 + j;
                psum_s[(size_t)o * NCOL + blk2] = s;
                psum_q[(size_t)o * NCOL + blk2] = q;
            }
        }
}

// ---------------- 4. reduce partials -> scale/shift ----------------
__global__ __launch_bounds__(256) void k_stats2(const float* __restrict__ psum_s,
                                                const float* __restrict__ psum_q,
                                                const float* __restrict__ gamma,
                                                const float* __restrict__ beta,
                                                float* __restrict__ scaleArr,
                                                float* __restrict__ shiftArr) {
    int o = blockIdx.x;
    int t = threadIdx.x;
    float s = 0.f, q = 0.f;
    for (int i = t; i < NCOL; i += 256) {
        s += psum_s[(size_t)o * NCOL + i];
        q += psum_q[(size_t)o * NCOL + i];
    }
    __shared__ float r1[256], r2[256];
    r1[t] = s; r2[t] = q;
    __syncthreads();
    for (int st = 128; st > 0; st >>= 1) {
        if (t < st) { r1[t] += r1[t + st]; r2[t] += r2[t + st]; }
        __syncthreads();
    }
    if (t == 0) {
        float inv = 1.f / (float)NPOS;
        float mean = r1[0] * inv;
        float var  = r2[0] * inv - mean * mean;
        float sc = gamma[o] * rsqrtf(var + EPSV);
        scaleArr[o] = sc;
        shiftArr[o] = beta[o] - mean * sc;
    }
}

// ---------------- 5. normalize + ReLU (in place on d_out) ----------------
__global__ __launch_bounds__(256) void k_norm(float* __restrict__ y,
                                              const float* __restrict__ scaleArr,
                                              const float* __restrict__ shiftArr) {
    const int total4 = NBAT * CH * (HW / 4);
    for (int i = blockIdx.x * 256 + threadIdx.x; i < total4; i += gridDim.x * 256) {
        int o = (i / (HW / 4)) & 255;
        float sc = scaleArr[o], sh = shiftArr[o];
        float4 v = ((const float4*)y)[i];
        float4 r;
        r.x = fmaxf(v.x * sc + sh, 0.f);
        r.y = fmaxf(v.y * sc + sh, 0.f);
        r.z = fmaxf(v.z * sc + sh, 0.f);
        r.w = fmaxf(v.w * sc + sh, 0.f);
        ((float4*)y)[i] = r;
    }
}

extern "C" void kernel_launch(void* const* d_in, const int* in_sizes, int n_in,
                              void* d_out, int out_size, void* d_ws, size_t ws_size,
                              hipStream_t stream) {
    const float* x     = (const float*)d_in[0];
    const float* off   = (const float*)d_in[1];
    const float* wgt   = (const float*)d_in[2];
    const float* gamma = (const float*)d_in[3];
    const float* beta  = (const float*)d_in[4];
    float* out = (float*)d_out;     // pre-BN conv output, normalized in place
    char* ws = (char*)d_ws;

    // workspace layout (min ~30.1 MB)
    unsigned short* W2 = (unsigned short*)(ws + 0);          //  1,179,648 B
    unsigned short* xt = (unsigned short*)(ws + 1179648);    // 25,690,112 B
    float* psum_s      = (float*)(ws + 26869760);            //  1,605,632 B
    float* psum_q      = (float*)(ws + 28475392);            //  1,605,632 B
    float* scaleArr    = (float*)(ws + 30081024);            //      1,024 B
    float* shiftArr    = (float*)(ws + 30082048);            //      1,024 B

    k_transpose<<<dim3(49, 4, 16), 256, 0, stream>>>(x, xt);
    k_w2<<<2304, 256, 0, stream>>>(wgt, W2);
    k_fgemm<<<dim3(49, 16), 512, 0, stream>>>(xt, off, W2, out, psum_s, psum_q);
    k_stats2<<<256, 256, 0, stream>>>(psum_s, psum_q, gamma, beta, scaleArr, shiftArr);
    k_norm<<<2048, 256, 0, stream>>>(out, scaleArr, shiftArr);
}